// Round 4
// baseline (555.258 us; speedup 1.0000x reference)
//
#include <hip/hip_runtime.h>

// receptive_attention: out[b,h,i,j] = (|i-j| <= 128) ? dot(q[i,:], k[j,:]) : 0
// B=2 H=16 L=2048 D=64 fp32.
//
// R7: ONE WRITER PER CONTIGUOUS OUTPUT REGION (fill-identical store stream).
// Evidence: R0/R3/R6 all ~207-215us kernel vs ~92us traffic floor; R6 proved
// the band compute is NOT LDS-bound (4x fewer LDS instrs -> +0); the harness
// fill streams 6.2 TB/s at 10% occupancy with monotone full-line writes. Our
// previous kernels shredded every 8KB row across ~7 blocks (5x 256B band
// fragments + 2 zero writers). R7: one 512-thr block per (strip,bh) computes
// all <=5 band tiles (R6's verbatim swizzled-b128 4x4 micro-kernel, 2 groups
// x 256 thr, K-pair dbuf with register prefetch), flushes masked acc into
// Band[32][320] LDS (aliases the dead Q/K arena), then sweeps FULL 8KB rows
// linearly (zeros fused: thread t writes col 4t, rows sequential) -> one
// monotone contiguous 512KB stream per block.
// MEASURED-BAD, do not reintroduce: __builtin_nontemporal_store (R2: RMW
// amplification), scalar-write transposed-K staging (8-way conflicts), R5's
// 4x2-micro 1024-thr blocks w/ band-only sweep + separate zero blocks (567us),
// >64KB static __shared__ (R4: container-killing launch failure).

constexpr int L = 2048;
constexpr int D = 64;
constexpr int R = 128;
constexpr int TILE = 64;
constexpr int NT = L / TILE;            // 32
constexpr int ARENA = 3 * TILE * 64;    // 12288 floats = 48 KB

__global__ __launch_bounds__(512, 4)
void receptive_attention_kernel(const float* __restrict__ q,
                                const float* __restrict__ k,
                                float* __restrict__ out) {
    const int ti = blockIdx.x;          // 64-row strip
    const int bh = blockIdx.y;
    const int t  = threadIdx.x;

    const int jt_lo = (ti - 2 > 0) ? (ti - 2) : 0;
    const int jt_hi = (ti + 2 < NT - 1) ? (ti + 2) : (NT - 1);
    const int ntj   = jt_hi - jt_lo + 1;        // 3..5
    const int c0    = jt_lo * TILE;             // band start col (64-aligned)

    // LDS arena: compute phase Qs[0..4096) + Kg g=0 [4096..8192) g=1 [8192..12288)
    //            flush/sweep Band[32][320] = 10240 floats (arena dead by then)
    __shared__ __align__(16) float smem[ARENA];
    float* Qs = smem;
    const int g = t >> 8;               // tile-group 0/1
    const int s = t & 255;              // lane in group
    float* Kg = smem + TILE * 64 + g * TILE * 64;

    const float* qTile = q + ((size_t)bh * L + (size_t)ti * TILE) * D;
    const float* kBase = k + ((size_t)bh * L + (size_t)jt_lo * TILE) * D;

    // ---- stage Q (all 512 thr) + K pair 0 (tiles 0,1 always valid: ntj>=3) ----
    #pragma unroll
    for (int it = 0; it < 2; ++it) {
        int idx  = t + it * 512;        // 0..1023
        int row  = idx >> 4;
        int col4 = idx & 15;
        float4 qv = *reinterpret_cast<const float4*>(qTile + row * D + col4 * 4);
        int wb = (col4 ^ (row >> 2)) & 15;
        *reinterpret_cast<float4*>(&Qs[row * 64 + wb * 4]) = qv;
    }
    {
        const float* kt = kBase + (size_t)g * TILE * D;
        #pragma unroll
        for (int it = 0; it < 4; ++it) {
            int idx  = s + it * 256;
            int row  = idx >> 4;
            int col4 = idx & 15;
            float4 kv = *reinterpret_cast<const float4*>(kt + row * D + col4 * 4);
            int wb = (col4 ^ (row >> 2)) & 15;
            *reinterpret_cast<float4*>(&Kg[row * 64 + wb * 4]) = kv;
        }
    }
    __syncthreads();

    const int tr = (s >> 4) * 4;        // micro-tile base row (0..60)
    const int tc = (s & 15) * 4;        // micro-tile base col (0..60)
    const int xq = (s >> 4) & 15;       // (row>>2) for rows tr..tr+3
    const int xk = s & 15;              // (col>>2) for cols tc..tc+3

    float acc[3][4][4] = {};            // acc[p] = tile (2p+g), static-indexed

    #pragma unroll
    for (int p = 0; p < 3; ++p) {
        // register prefetch of this group's next-pair tile (issued pre-compute)
        float4 nf0, nf1, nf2, nf3;
        const int ntt = 2 * (p + 1) + g;
        const bool npv = (p < 2) && (ntt < ntj);
        if (npv) {
            const float* kt = kBase + (size_t)ntt * TILE * D;
            nf0 = *reinterpret_cast<const float4*>(kt + ((s + 0)   >> 4) * D + ((s + 0)   & 15) * 4);
            nf1 = *reinterpret_cast<const float4*>(kt + ((s + 256) >> 4) * D + ((s + 256) & 15) * 4);
            nf2 = *reinterpret_cast<const float4*>(kt + ((s + 512) >> 4) * D + ((s + 512) & 15) * 4);
            nf3 = *reinterpret_cast<const float4*>(kt + ((s + 768) >> 4) * D + ((s + 768) & 15) * 4);
        }

        const int tt = 2 * p + g;
        if (tt < ntj) {
            #pragma unroll 4
            for (int b = 0; b < 16; ++b) {          // d0 = 4*b
                float4 qv[4], kv[4];
                const int qb = ((b ^ xq) & 15) * 4;
                const int kb = ((b ^ xk) & 15) * 4;
                #pragma unroll
                for (int r = 0; r < 4; ++r)
                    qv[r] = *reinterpret_cast<const float4*>(&Qs[(tr + r) * 64 + qb]);
                #pragma unroll
                for (int c = 0; c < 4; ++c)
                    kv[c] = *reinterpret_cast<const float4*>(&Kg[(tc + c) * 64 + kb]);
                #pragma unroll
                for (int rr = 0; rr < 4; ++rr) {
                    #pragma unroll
                    for (int cc = 0; cc < 4; ++cc) {
                        // d-order preserved: four separate += (bit-exact)
                        acc[p][rr][cc] += qv[rr].x * kv[cc].x;
                        acc[p][rr][cc] += qv[rr].y * kv[cc].y;
                        acc[p][rr][cc] += qv[rr].z * kv[cc].z;
                        acc[p][rr][cc] += qv[rr].w * kv[cc].w;
                    }
                }
            }
        }
        __syncthreads();                // group done reading Kg
        if (npv) {
            int r0 = (s + 0) >> 4,   c4_0 = (s + 0) & 15;
            int r1 = (s + 256) >> 4, c4_1 = (s + 256) & 15;
            int r2 = (s + 512) >> 4, c4_2 = (s + 512) & 15;
            int r3 = (s + 768) >> 4, c4_3 = (s + 768) & 15;
            *reinterpret_cast<float4*>(&Kg[r0 * 64 + (((c4_0 ^ (r0 >> 2)) & 15)) * 4]) = nf0;
            *reinterpret_cast<float4*>(&Kg[r1 * 64 + (((c4_1 ^ (r1 >> 2)) & 15)) * 4]) = nf1;
            *reinterpret_cast<float4*>(&Kg[r2 * 64 + (((c4_2 ^ (r2 >> 2)) & 15)) * 4]) = nf2;
            *reinterpret_cast<float4*>(&Kg[r3 * 64 + (((c4_3 ^ (r3 >> 2)) & 15)) * 4]) = nf3;
        }
        __syncthreads();                // next tile staged
    }

    // ---- flush+sweep, two 32-row halves; Band aliases the dead arena ----
    float* Band = smem;                 // [32][320]
    const int gi0 = ti * TILE + tr;
    const int bandlo4 = c0 / 4;         // first band float4 index in a row
    const int bandn4  = ntj * 16;       // band float4s per row (48/64/80)
    const int rel     = t - bandlo4;    // this thread's band f4, if in range
    float* rowBase0 = out + (size_t)bh * L * L + (size_t)ti * TILE * L;

    #pragma unroll
    for (int half = 0; half < 2; ++half) {
        const int rlo = half * 32;
        if (tr >= rlo && tr < rlo + 32) {
            #pragma unroll
            for (int p = 0; p < 3; ++p) {
                const int tt = 2 * p + g;
                if (tt < ntj) {
                    const int gj0 = (jt_lo + tt) * TILE + tc;
                    #pragma unroll
                    for (int rr = 0; rr < 4; ++rr) {
                        float4 v;
                        float* vp = &v.x;
                        #pragma unroll
                        for (int cc = 0; cc < 4; ++cc) {
                            int diff = gi0 + rr - (gj0 + cc);
                            if (diff < 0) diff = -diff;
                            vp[cc] = (diff <= R) ? acc[p][rr][cc] : 0.f;
                        }
                        *reinterpret_cast<float4*>(
                            &Band[(tr - rlo + rr) * 320 + tt * 64 + tc]) = v;
                    }
                }
            }
        }
        __syncthreads();

        // linear full-row sweep: rows rlo..rlo+31, thread t owns col 4t;
        // per-row the block writes one contiguous 8KB line; rows sequential
        // -> one monotone 256KB stream per half (fill-identical pattern).
        float* rowBase = rowBase0 + (size_t)rlo * L;
        #pragma unroll 4
        for (int r = 0; r < 32; ++r) {
            float4 v = make_float4(0.f, 0.f, 0.f, 0.f);
            if (rel >= 0 && rel < bandn4)
                v = *reinterpret_cast<float4*>(&Band[r * 320 + rel * 4]);
            *reinterpret_cast<float4*>(rowBase + (size_t)r * L + t * 4) = v;
        }
        __syncthreads();                // sweep reads done before next flush
    }
}

extern "C" void kernel_launch(void* const* d_in, const int* in_sizes, int n_in,
                              void* d_out, int out_size, void* d_ws, size_t ws_size,
                              hipStream_t stream) {
    const float* q = (const float*)d_in[0];
    const float* k = (const float*)d_in[1];
    float* out = (float*)d_out;

    dim3 grid(NT, 32);      // x=strip, y=bh; one block writes one 512KB region
    receptive_attention_kernel<<<grid, 512, 0, stream>>>(q, k, out);
}